// Round 10
// baseline (353.523 us; speedup 1.0000x reference)
//
#include <hip/hip_runtime.h>
#include <math.h>

#define ROWS 18496          // bt*J*N = 64*17*17
#define SCALE 0.17677669529663687f  // 1/sqrt(32)
#define PSTRIDE 4928        // padded 4913 -> 16B-aligned per-bh prob stride

typedef unsigned short ushort_t;
typedef __attribute__((ext_vector_type(8))) short short8;
typedef __attribute__((ext_vector_type(8))) unsigned short us8;
typedef __attribute__((ext_vector_type(4))) float f32x4;

__device__ __forceinline__ void fma4(float4& d, float s, const float4& v) {
    d.x = fmaf(s, v.x, d.x); d.y = fmaf(s, v.y, d.y);
    d.z = fmaf(s, v.z, d.z); d.w = fmaf(s, v.w, d.w);
}
__device__ __forceinline__ float dot4(const float4& a, const float4& b) {
    return a.x*b.x + a.y*b.y + a.z*b.z + a.w*b.w;
}

__device__ __forceinline__ ushort_t f2bf(float x) {
    union { float f; unsigned u; } v; v.f = x;
    unsigned r = v.u + 0x7fffu + ((v.u >> 16) & 1u);
    return (ushort_t)(r >> 16);
}
__device__ __forceinline__ float bf2f(ushort_t b) {
    union { unsigned u; float f; } v; v.u = ((unsigned)b) << 16; return v.f;
}

__device__ __forceinline__ void gl_lds16(const void* g, void* l) {
    __builtin_amdgcn_global_load_lds(
        (const __attribute__((address_space(1))) void*)g,
        (__attribute__((address_space(3))) void*)l, 16, 0, 0);
}

// y2 layout: [row][1536] ushorts = [row][chunk=h*3+sec][hi:32|lo:32].
__device__ __forceinline__ void store_y2(ushort_t* __restrict__ y2,
    size_t row, int chunk, int q8, const float4& a0, const float4& a1)
{
    us8 h, l;
    h[0] = f2bf(a0.x); l[0] = f2bf(a0.x - bf2f(h[0]));
    h[1] = f2bf(a0.y); l[1] = f2bf(a0.y - bf2f(h[1]));
    h[2] = f2bf(a0.z); l[2] = f2bf(a0.z - bf2f(h[2]));
    h[3] = f2bf(a0.w); l[3] = f2bf(a0.w - bf2f(h[3]));
    h[4] = f2bf(a1.x); l[4] = f2bf(a1.x - bf2f(h[4]));
    h[5] = f2bf(a1.y); l[5] = f2bf(a1.y - bf2f(h[5]));
    h[6] = f2bf(a1.z); l[6] = f2bf(a1.z - bf2f(h[6]));
    h[7] = f2bf(a1.w); l[7] = f2bf(a1.w - bf2f(h[7]));
    size_t off = row * 1536 + chunk * 64 + q8;
    *(us8*)&y2[off]      = h;
    *(us8*)&y2[off + 32] = l;
}

// ---------------- merged conversion kernel ----------------------------
__global__ __launch_bounds__(256) void k_cvt_xw(
    const float4* __restrict__ x, ushort4* __restrict__ xhi, ushort4* __restrict__ xlo,
    const float* __restrict__ W, ushort_t* __restrict__ bh, ushort_t* __restrict__ bl)
{
    if (blockIdx.x < 4624) {
        int i = blockIdx.x * 256 + threadIdx.x;
        float4 v = x[i];
        ushort4 h, l;
        h.x = f2bf(v.x); l.x = f2bf(v.x - bf2f(h.x));
        h.y = f2bf(v.y); l.y = f2bf(v.y - bf2f(h.y));
        h.z = f2bf(v.z); l.z = f2bf(v.z - bf2f(h.z));
        h.w = f2bf(v.w); l.w = f2bf(v.w - bf2f(h.w));
        xhi[i] = h; xlo[i] = l;
    } else {
        int o = blockIdx.x - 4624;   // 0..1279
        int kk = threadIdx.x;        // 0..255
        int col = (o & 255) * 5 + (o >> 8);
        float v = W[(size_t)kk * 1280 + col];
        ushort_t hh = f2bf(v);
        bh[(size_t)o * 256 + kk] = hh;
        bl[(size_t)o * 256 + kk] = f2bf(v - bf2f(hh));
    }
}

// Wp -> transposed bf16 [n][k_eff], k_eff permuted for the y2 interleave.
__global__ __launch_bounds__(256) void k_cvt_wp(
    const float* __restrict__ W, ushort_t* __restrict__ bh, ushort_t* __restrict__ bl)
{
    int n = blockIdx.x;          // 0..255
    for (int k = threadIdx.x; k < 768; k += 256) {
        int j = k >> 5, cc = k & 31;
        int h = j / 3, sec = j % 3;
        int ko = sec * 256 + h * 32 + cc;
        float v = W[(size_t)ko * 256 + n];
        ushort_t hh = f2bf(v);
        bh[(size_t)n * 768 + k] = hh;
        bl[(size_t)n * 768 + k] = f2bf(v - bf2f(hh));
    }
}

// ---------------- split-bf16 MFMA GEMM --------------------------------
template<int BM, int BN, int K, int MODE, int AI>
__global__ __launch_bounds__(256) void k_gemm(
    const ushort_t* __restrict__ Ahi, const ushort_t* __restrict__ Alo,
    const ushort_t* __restrict__ Bhi, const ushort_t* __restrict__ Blo,
    const float* __restrict__ aux,
    float* __restrict__ out)
{
    constexpr int MT = BM / 32;
    constexpr int NT = BN / 32;
    __shared__ __attribute__((aligned(16))) ushort_t sAh[BM * 32];
    __shared__ __attribute__((aligned(16))) ushort_t sAl[BM * 32];
    __shared__ __attribute__((aligned(16))) ushort_t sBh[BN * 32];
    __shared__ __attribute__((aligned(16))) ushort_t sBl[BN * 32];

    const int t = threadIdx.x;
    const int lane = t & 63;
    const int ln = lane & 15, quad = lane >> 4;
    const int wave = t >> 6;
    const int wm = wave >> 1, wn = wave & 1;
    const int m0 = blockIdx.y * BM, n0 = blockIdx.x * BN;

    f32x4 acc[MT][NT];
#pragma unroll
    for (int i = 0; i < MT; ++i)
#pragma unroll
        for (int j = 0; j < NT; ++j) acc[i][j] = (f32x4){0.f, 0.f, 0.f, 0.f};

    for (int kb = 0; kb < K; kb += 32) {
        __syncthreads();
#pragma unroll
        for (int s = t; s < BM * 4; s += 256) {
            int row = s >> 2, kc = s & 3;
            int gr = m0 + row; if (gr > ROWS - 1) gr = ROWS - 1;
            int lb = (s & ~63) * 16;
            if (AI) {
                size_t gb = (size_t)gr * 3072 + (kb >> 5) * 128 + kc * 16;
                gl_lds16((const char*)Ahi + gb,      (char*)sAh + lb);
                gl_lds16((const char*)Ahi + gb + 64, (char*)sAl + lb);
            } else {
                size_t gb = ((size_t)gr * K + kb) * 2 + kc * 16;
                gl_lds16((const char*)Ahi + gb, (char*)sAh + lb);
                gl_lds16((const char*)Alo + gb, (char*)sAl + lb);
            }
        }
#pragma unroll
        for (int s = t; s < BN * 4; s += 256) {
            int row = s >> 2, kc = s & 3;
            size_t gb = ((size_t)(n0 + row) * K + kb) * 2 + kc * 16;
            int lb = (s & ~63) * 16;
            gl_lds16((const char*)Bhi + gb, (char*)sBh + lb);
            gl_lds16((const char*)Blo + gb, (char*)sBl + lb);
        }
        __syncthreads();

        short8 ah[MT], al[MT], bh[NT], bl[NT];
#pragma unroll
        for (int i = 0; i < MT; ++i) {
            int off = (wm * (BM / 2) + i * 16 + ln) * 32 + quad * 8;
            ah[i] = *(const short8*)&sAh[off];
            al[i] = *(const short8*)&sAl[off];
        }
#pragma unroll
        for (int j = 0; j < NT; ++j) {
            int off = (wn * (BN / 2) + j * 16 + ln) * 32 + quad * 8;
            bh[j] = *(const short8*)&sBh[off];
            bl[j] = *(const short8*)&sBl[off];
        }
#pragma unroll
        for (int i = 0; i < MT; ++i)
#pragma unroll
            for (int j = 0; j < NT; ++j) {
                acc[i][j] = __builtin_amdgcn_mfma_f32_16x16x32_bf16(ah[i], bh[j], acc[i][j], 0, 0, 0);
                acc[i][j] = __builtin_amdgcn_mfma_f32_16x16x32_bf16(ah[i], bl[j], acc[i][j], 0, 0, 0);
                acc[i][j] = __builtin_amdgcn_mfma_f32_16x16x32_bf16(al[i], bh[j], acc[i][j], 0, 0, 0);
            }
    }

#pragma unroll
    for (int i = 0; i < MT; ++i) {
#pragma unroll
        for (int r = 0; r < 4; ++r) {
            int gm = m0 + wm * (BM / 2) + i * 16 + quad * 4 + r;
            if (gm >= ROWS) continue;
            if (MODE == 0) {
                int jn = gm % 289;
                const float* Mrow = &aux[(size_t)jn * 256];
#pragma unroll
                for (int j = 0; j < NT; ++j) {
                    int gn = n0 + wn * (BN / 2) + j * 16 + ln;
                    out[(size_t)gm * 1280 + gn] = acc[i][j][r] * Mrow[gn & 255];
                }
            } else {
#pragma unroll
                for (int j = 0; j < NT; ++j) {
                    int gn = n0 + wn * (BN / 2) + j * 16 + ln;
                    out[(size_t)gm * 256 + gn] = acc[i][j][r] + aux[gn];
                }
            }
        }
    }
}

// ---------------- k_scores: probs only, 3 blocks/CU ----------------------
// Block per (b,h), 320 threads, 41 KB LDS. Scores + both softmaxes fully in
// registers; probs staged in LDS then written coalesced to padded global.
__global__ __launch_bounds__(320) void k_scores(
    const float* __restrict__ qkv5,
    float* __restrict__ pS, float* __restrict__ pV)
{
    __shared__ __attribute__((aligned(16))) float sm[10404]; // k-tile 289*36; reused for out-staging
    const int t  = threadIdx.x;
    const int bh = blockIdx.x;
    const int b  = bh >> 3, h = bh & 7;
    const size_t rowbase = (size_t)b * 289;
    const int colq = h * 32;

    // stage K tile: row p at stride 36 (16B-multiple, bank-spread)
    for (int idx = t; idx < 2312; idx += 320) {
        int p = idx >> 3, c = idx & 7;
        *(float4*)&sm[p * 36 + c * 4] =
            *(const float4*)&qkv5[(rowbase + p) * 1280 + 256 + colq + c * 4];
    }
    float4 q[8];
    if (t < 289) {
        const float* qp = &qkv5[(rowbase + t) * 1280 + colq];
#pragma unroll
        for (int c = 0; c < 8; ++c) q[c] = *(const float4*)&qp[c * 4];
    }
    __syncthreads();

    float accS[17], accV[17];
    const int a = t / 17, bb = t % 17;
    if (t < 289) {
#pragma unroll
        for (int kk = 0; kk < 17; ++kk) {
            const float4* r = (const float4*)&sm[(kk * 17 + bb) * 36];
            float s = 0.f;
#pragma unroll
            for (int c = 0; c < 8; ++c) s += dot4(q[c], r[c]);
            accS[kk] = s * SCALE;
        }
#pragma unroll
        for (int mm = 0; mm < 17; ++mm) {
            const float4* r = (const float4*)&sm[(a * 17 + mm) * 36];
            float s = 0.f;
#pragma unroll
            for (int c = 0; c < 8; ++c) s += dot4(q[c], r[c]);
            accV[mm] = s * SCALE;
        }
        // softmax both, in registers
        float mx = accS[0];
#pragma unroll
        for (int i = 1; i < 17; ++i) mx = fmaxf(mx, accS[i]);
        float sum = 0.f;
#pragma unroll
        for (int i = 0; i < 17; ++i) { accS[i] = expf(accS[i] - mx); sum += accS[i]; }
        float inv = 1.f / sum;
#pragma unroll
        for (int i = 0; i < 17; ++i) accS[i] *= inv;
        mx = accV[0];
#pragma unroll
        for (int i = 1; i < 17; ++i) mx = fmaxf(mx, accV[i]);
        sum = 0.f;
#pragma unroll
        for (int i = 0; i < 17; ++i) { accV[i] = expf(accV[i] - mx); sum += accV[i]; }
        inv = 1.f / sum;
#pragma unroll
        for (int i = 0; i < 17; ++i) accV[i] *= inv;
    }
    __syncthreads();   // k-tile reads done; reuse sm as staging

    if (t < 289) {
        // aS layout [n=bb][j=a][k]; aV layout [j=a][n=bb][m] at offset 4916 (aligned)
#pragma unroll
        for (int kk = 0; kk < 17; ++kk) sm[bb * 289 + a * 17 + kk] = accS[kk];
#pragma unroll
        for (int mm = 0; mm < 17; ++mm) sm[4916 + a * 289 + bb * 17 + mm] = accV[mm];
    }
    __syncthreads();

    const size_t gb = (size_t)bh * PSTRIDE;
    for (int idx = t; idx < 1229; idx += 320) {
        if (idx < 1228) {
            *(float4*)&pS[gb + idx * 4] = *(const float4*)&sm[idx * 4];
            *(float4*)&pV[gb + idx * 4] = *(const float4*)&sm[4916 + idx * 4];
        } else {
            pS[gb + 4912] = sm[4912];
            pV[gb + 4912] = sm[4916 + 4912];
        }
    }
}

// ---------------- k_combine: 1536 blocks, kind = bx%3 --------------------
__device__ __forceinline__ void stage_load(const float* __restrict__ qkv5,
    size_t rowbase, int colbase, int t, float4* pf)
{
#pragma unroll
    for (int r = 0; r < 4; ++r) {
        int idx = t + r * 320;
        if (idx < 1156) {
            int p = idx >> 2, c = idx & 3;
            pf[r] = *(const float4*)&qkv5[(rowbase + p) * 1280 + colbase + c * 8];
        }
    }
}
__device__ __forceinline__ void stage_store(float* buf, int t, const float4* pf)
{
#pragma unroll
    for (int r = 0; r < 4; ++r) {
        int idx = t + r * 320;
        if (idx < 1156) {
            int p = idx >> 2, c = idx & 3;
            *(float4*)&buf[p * 20 + c * 4] = pf[r];
        }
    }
}

__device__ __forceinline__ void p4_round(
    const float* aS, const float* ebS, const float* buf, int t, float4 out[2][2])
{
#pragma unroll
    for (int ti = 0; ti < 2; ++ti) {
        int u = t + ti * 320;
        if (u >= 612) break;
        int cc = (u & 3) * 4, rest = u >> 2;
        int n = rest % 17, jp = rest / 17;
        int j0 = jp * 2;
        int j1 = (j0 + 1 > 16) ? 16 : j0 + 1;
        float w0[17], w1[17];
        float s0 = 0.f, s1 = 0.f;
        const float* as0 = &aS[n * 289 + j0 * 17];
        const float* as1 = &aS[n * 289 + j1 * 17];
        const float* e0 = &ebS[j0 * 17];
        const float* e1 = &ebS[j1 * 17];
#pragma unroll
        for (int kk = 0; kk < 17; ++kk) {
            w0[kk] = as0[kk] * e0[kk]; s0 += w0[kk];
            w1[kk] = as1[kk] * e1[kk]; s1 += w1[kk];
        }
        float i0 = 1.f / s0, i1 = 1.f / s1;
        float4 a0 = {0,0,0,0}, a1 = {0,0,0,0};
        for (int kk = 0; kk < 17; ++kk) {
            float4 v = *(const float4*)&buf[(kk * 17 + n) * 20 + cc];
            fma4(a0, w0[kk], v);
            fma4(a1, w1[kk], v);
        }
        a0.x *= i0; a0.y *= i0; a0.z *= i0; a0.w *= i0;
        a1.x *= i1; a1.y *= i1; a1.z *= i1; a1.w *= i1;
        out[ti][0] = a0; out[ti][1] = a1;
    }
}

__device__ __forceinline__ void p5_round(
    const float* aV, const float* ebV, const float* buf, int t, float4 out[2][2])
{
#pragma unroll
    for (int ti = 0; ti < 2; ++ti) {
        int u = t + ti * 320;
        if (u >= 612) break;
        int cc = (u & 3) * 4, rest = u >> 2;
        int j = rest % 17, np = rest / 17;
        int n0 = np * 2;
        int n1 = (n0 + 1 > 16) ? 16 : n0 + 1;
        float w0[17], w1[17];
        float s0 = 0.f, s1 = 0.f;
        const float* av0 = &aV[j * 289 + n0 * 17];
        const float* av1 = &aV[j * 289 + n1 * 17];
        const float* e0 = &ebV[n0 * 17];
        const float* e1 = &ebV[n1 * 17];
#pragma unroll
        for (int mm = 0; mm < 17; ++mm) {
            w0[mm] = av0[mm] * e0[mm]; s0 += w0[mm];
            w1[mm] = av1[mm] * e1[mm]; s1 += w1[mm];
        }
        float i0 = 1.f / s0, i1 = 1.f / s1;
        float4 a0 = {0,0,0,0}, a1 = {0,0,0,0};
        for (int mm = 0; mm < 17; ++mm) {
            float4 v = *(const float4*)&buf[(j * 17 + mm) * 20 + cc];
            fma4(a0, w0[mm], v);
            fma4(a1, w1[mm], v);
        }
        a0.x *= i0; a0.y *= i0; a0.z *= i0; a0.w *= i0;
        a1.x *= i1; a1.y *= i1; a1.z *= i1; a1.w *= i1;
        out[ti][0] = a0; out[ti][1] = a1;
    }
}

__global__ __launch_bounds__(320) void k_combine(
    const float* __restrict__ qkv5,
    const float* __restrict__ pS, const float* __restrict__ pV,
    const float* __restrict__ A_s, const float* __restrict__ A_v,
    const float* __restrict__ adjS, const float* __restrict__ adjV,
    ushort_t* __restrict__ y2)
{
    __shared__ __attribute__((aligned(16))) float sm[15648];
    // kind0: aS=sm[0..4913), aV=sm[4916..9829), buf=sm[9856..15636)
    // kind1/2: probs=sm[0..4913), eb=sm[4916..5205), buf=sm[9856..15636)
    float* buf = sm + 9856;
    const int t  = threadIdx.x;
    const int bx = blockIdx.x;
    const int kind = bx % 3;
    const int bh = bx / 3;
    const int b  = bh >> 3, h = bh & 7;
    const size_t rowbase = (size_t)b * 289;
    const int colq = h * 32;
    const size_t pb_g = (size_t)bh * PSTRIDE;
    float4 pf[4];

    if (kind == 0) {
        // -------- x_vsv -> y2 sec 0 --------
        stage_load(qkv5, rowbase, 1024 + colq + 0, t, pf);    // vsv even quads
        for (int idx = t; idx < 1229; idx += 320) {
            if (idx < 1228) {
                *(float4*)&sm[idx * 4]        = *(const float4*)&pS[pb_g + idx * 4];
                *(float4*)&sm[4916 + idx * 4] = *(const float4*)&pV[pb_g + idx * 4];
            } else {
                sm[4912]        = pS[pb_g + 4912];
                sm[4916 + 4912] = pV[pb_g + 4912];
            }
        }
        stage_store(buf, t, pf);
        stage_load(qkv5, rowbase, 1024 + colq + 4, t, pf);    // vsv odd quads
        __syncthreads();

        const float* aS = sm;
        const float* aV = sm + 4916;
        const int c4 = (t & 3) * 4;
        const int q8 = (t & 3) * 8;
        const int pb = (t >> 2) * 4;
        const int nv = (t < 292) ? ((289 - pb < 4) ? (289 - pb) : 4) : 0;
        int jj3[4], nn3[4];
        float eV[4][17];
        float4 acc3[2][4];
        if (t < 292) {
#pragma unroll
            for (int g = 0; g < 4; ++g) {
                int p = pb + g; if (p > 288) p = 288;
                jj3[g] = p / 17; nn3[g] = p % 17;
                const float* src = &aV[jj3[g] * 289 + nn3[g] * 17];
#pragma unroll
                for (int m = 0; m < 17; ++m) eV[g][m] = src[m];
            }
#pragma unroll
            for (int g = 0; g < 4; ++g) acc3[0][g] = (float4){0,0,0,0};
            for (int kk = 0; kk < 17; ++kk) {
                float4 tg[4];
#pragma unroll
                for (int g = 0; g < 4; ++g) tg[g] = (float4){0,0,0,0};
#pragma unroll
                for (int m = 0; m < 17; ++m) {
                    float4 v = *(const float4*)&buf[(kk * 17 + m) * 20 + c4];
#pragma unroll
                    for (int g = 0; g < 4; ++g) fma4(tg[g], eV[g][m], v);
                }
#pragma unroll
                for (int g = 0; g < 4; ++g)
                    fma4(acc3[0][g], aS[nn3[g] * 289 + jj3[g] * 17 + kk], tg[g]);
            }
        }
        __syncthreads();
        stage_store(buf, t, pf);
        __syncthreads();
        if (t < 292) {
#pragma unroll
            for (int g = 0; g < 4; ++g) acc3[1][g] = (float4){0,0,0,0};
            for (int kk = 0; kk < 17; ++kk) {
                float4 tg[4];
#pragma unroll
                for (int g = 0; g < 4; ++g) tg[g] = (float4){0,0,0,0};
#pragma unroll
                for (int m = 0; m < 17; ++m) {
                    float4 v = *(const float4*)&buf[(kk * 17 + m) * 20 + c4];
#pragma unroll
                    for (int g = 0; g < 4; ++g) fma4(tg[g], eV[g][m], v);
                }
#pragma unroll
                for (int g = 0; g < 4; ++g)
                    fma4(acc3[1][g], aS[nn3[g] * 289 + jj3[g] * 17 + kk], tg[g]);
            }
            for (int g = 0; g < nv; ++g)
                store_y2(y2, rowbase + pb + g, h * 3 + 0, q8, acc3[0][g], acc3[1][g]);
        }
    } else if (kind == 1) {
        // -------- x_vs -> y2 sec 1 --------
        stage_load(qkv5, rowbase, 512 + colq + 0, t, pf);
        for (int idx = t; idx < 1229; idx += 320) {
            if (idx < 1228)
                *(float4*)&sm[idx * 4] = *(const float4*)&pS[pb_g + idx * 4];
            else
                sm[4912] = pS[pb_g + 4912];
        }
        for (int idx = t; idx < 289; idx += 320) {
            int jj = idx / 17, kk = idx % 17;
            float bias = 0.5f * ((A_s[jj*17+kk] + adjS[jj*17+kk]) + (A_s[kk*17+jj] + adjS[kk*17+jj]));
            sm[4916 + idx] = expf(bias);
        }
        stage_store(buf, t, pf);
        stage_load(qkv5, rowbase, 512 + colq + 4, t, pf);
        __syncthreads();

        float4 hold[2][2][2];
        p4_round(sm, sm + 4916, buf, t, hold[0]);
        __syncthreads();
        stage_store(buf, t, pf);
        __syncthreads();
        p4_round(sm, sm + 4916, buf, t, hold[1]);
#pragma unroll
        for (int ti = 0; ti < 2; ++ti) {
            int u = t + ti * 320;
            if (u >= 612) break;
            int qq8 = (u & 3) * 8, rest = u >> 2;
            int n = rest % 17, jp = rest / 17;
            int j0 = jp * 2;
            store_y2(y2, rowbase + j0 * 17 + n, h * 3 + 1, qq8, hold[0][ti][0], hold[1][ti][0]);
            if (j0 != 16)
                store_y2(y2, rowbase + (j0 + 1) * 17 + n, h * 3 + 1, qq8, hold[0][ti][1], hold[1][ti][1]);
        }
    } else {
        // -------- x_vv -> y2 sec 2 --------
        stage_load(qkv5, rowbase, 768 + colq + 0, t, pf);
        for (int idx = t; idx < 1229; idx += 320) {
            if (idx < 1228)
                *(float4*)&sm[idx * 4] = *(const float4*)&pV[pb_g + idx * 4];
            else
                sm[4912] = pV[pb_g + 4912];
        }
        for (int idx = t; idx < 289; idx += 320) {
            int jj = idx / 17, kk = idx % 17;
            float bias = 0.5f * ((A_v[jj*17+kk] + adjV[jj*17+kk]) + (A_v[kk*17+jj] + adjV[kk*17+jj]));
            sm[4916 + idx] = expf(bias);
        }
        stage_store(buf, t, pf);
        stage_load(qkv5, rowbase, 768 + colq + 4, t, pf);
        __syncthreads();

        float4 hold[2][2][2];
        p5_round(sm, sm + 4916, buf, t, hold[0]);
        __syncthreads();
        stage_store(buf, t, pf);
        __syncthreads();
        p5_round(sm, sm + 4916, buf, t, hold[1]);
#pragma unroll
        for (int ti = 0; ti < 2; ++ti) {
            int u = t + ti * 320;
            if (u >= 612) break;
            int qq8 = (u & 3) * 8, rest = u >> 2;
            int j = rest % 17, np = rest / 17;
            int n0 = np * 2;
            store_y2(y2, rowbase + j * 17 + n0, h * 3 + 2, qq8, hold[0][ti][0], hold[1][ti][0]);
            if (n0 != 16)
                store_y2(y2, rowbase + j * 17 + n0 + 1, h * 3 + 2, qq8, hold[0][ti][1], hold[1][ti][1]);
        }
    }
}

extern "C" void kernel_launch(void* const* d_in, const int* in_sizes, int n_in,
                              void* d_out, int out_size, void* d_ws, size_t ws_size,
                              hipStream_t stream)
{
    const float* x    = (const float*)d_in[0];
    const float* A_s  = (const float*)d_in[1];
    const float* A_v  = (const float*)d_in[2];
    const float* Wqkv = (const float*)d_in[3];
    const float* Wp   = (const float*)d_in[4];
    const float* bp   = (const float*)d_in[5];
    const float* M    = (const float*)d_in[6];
    const float* adjS = (const float*)d_in[7];
    const float* adjV = (const float*)d_in[8];
    float* out = (float*)d_out;

    char* w = (char*)d_ws;
    float*    qkv5  = (float*)w;                          // 94.7 MB, dead after combine
    ushort_t* wph   = (ushort_t*)w;                       // written after combine
    ushort_t* wpl   = (ushort_t*)(w + 393216);
    float* pS = (float*)(w + 94699520);                   // 512*4928*4 = 10.09 MB
    float* pV = (float*)(w + 94699520 + 10092544);        // ends 114.9 MB < 134.9
    char* R = w + 134946816;
    ushort_t* xhi = (ushort_t*)R;
    ushort_t* xlo = (ushort_t*)(R + 9469952);
    ushort_t* wqh = (ushort_t*)(R + 18939904);
    ushort_t* wql = (ushort_t*)(R + 19595264);
    ushort_t* y2  = (ushort_t*)R;   // 56.8 MB (after qkv gemm done)

    k_cvt_xw<<<dim3(5904), 256, 0, stream>>>((const float4*)x, (ushort4*)xhi, (ushort4*)xlo,
                                             Wqkv, wqh, wql);
    k_gemm<128, 128, 256, 0, 0><<<dim3(10, 145), 256, 0, stream>>>(xhi, xlo, wqh, wql, M, qkv5);
    k_scores<<<dim3(512), 320, 0, stream>>>(qkv5, pS, pV);
    k_combine<<<dim3(1536), 320, 0, stream>>>(qkv5, pS, pV, A_s, A_v, adjS, adjV, y2);
    k_cvt_wp<<<dim3(256), 256, 0, stream>>>(Wp, wph, wpl);
    k_gemm<128, 64, 768, 1, 1><<<dim3(4, 145), 256, 0, stream>>>(y2, y2, wph, wpl, bp, out);
}